// Round 9
// baseline (196.394 us; speedup 1.0000x reference)
//
#include <hip/hip_runtime.h>

// Truncated path signature, trunc=4, D=8, B=128, S=512 -- single fused kernel.
// Grid 1024 blocks (128 batches x 8 chunks of 64 steps), 128 threads (2 waves).
// Each block: compute chunk signature (lane=(a,b), wave id selects c-range via
// template<CB>), write to ws, threadfence, atomicAdd(cnt[b]). The 8th arriver
// of each batch folds the 8 chunk sigs (Chen product, order 0..7) -> d_out.
// cnt[] (128 ints at ws[0]) is zeroed by hipMemsetAsync each launch.
// Combiner thread (k=8a+b, half) folds the 4 tg = 64a+8b+4*half+j slices,
// sharing x1a/x1b/x2ab state and y1/y2ab loads across j.

constexpr int Bc = 128, Sc = 512, Tc = 511;
constexpr int NCH = 8, CH = 64;
constexpr int SIGSZ = 8 + 64 + 512 + 4096;        // 4680 floats (18720 B, 16B-mult)
constexpr int CNTF  = 128;                        // 128 ints = 512 B counter area

// ---------------- chunk inner loop (CB = 4*waveid, compile-time) ----------------
template <int CB>
__device__ __forceinline__ void run_loop(
    const float* __restrict__ dxs, int a, int bcoord,
    float acc4[4][8], float acc3[4], float& s2ab, float& s1a)
{
    float4 lo = *(const float4*)(dxs);
    float4 hi = *(const float4*)(dxs + 4);
    float da = dxs[a];
    float db = dxs[bcoord];

#pragma unroll 4
    for (int t = 0; t < CH; ++t) {
        const float* np = &dxs[(t + 1) * 8];      // row CH is the zero pad
        float4 nlo = *(const float4*)np;
        float4 nhi = *(const float4*)(np + 4);
        float nda = np[a];
        float ndb = np[bcoord];

        float r[8] = {lo.x, lo.y, lo.z, lo.w, hi.x, hi.y, hi.z, hi.w};
        float v = fmaf(s1a, 1.f / 6.f, da * (1.f / 24.f));
        float w = fmaf(0.5f, s1a, da * (1.f / 6.f));

#pragma unroll
        for (int j = 0; j < 4; ++j) {
            float dc = r[CB + j];
            float e = db * dc;
            float m = s2ab * dc;
            float K = fmaf(0.5f, m, acc3[j]);
            K = fmaf(e, v, K);
#pragma unroll
            for (int d = 0; d < 8; ++d)
                acc4[j][d] = fmaf(r[d], K, acc4[j][d]);
            acc3[j] += m;
            acc3[j] = fmaf(e, w, acc3[j]);
        }
        s2ab = fmaf(s1a, db, fmaf(0.5f * da, db, s2ab));
        s1a += da;

        lo = nlo; hi = nhi; da = nda; db = ndb;
    }
}

// ---------------- combiner (CB = 4*half, compile-time) ----------------
template <int CB>
__device__ __forceinline__ void combine_batch(
    const float* __restrict__ sigb,   // batch's 8 chunk sigs, stride SIGSZ
    float* __restrict__ o, int a, int b8)
{
    float x1a = 0.f, x1b = 0.f, x2ab = 0.f;
    float x1c[4] = {0.f, 0.f, 0.f, 0.f};
    float x2own[4] = {0.f, 0.f, 0.f, 0.f};
    float x3[4] = {0.f, 0.f, 0.f, 0.f};
    float x4[4][8];
#pragma unroll
    for (int j = 0; j < 4; ++j)
#pragma unroll
        for (int d = 0; d < 8; ++d) x4[j][d] = 0.f;

#pragma unroll 2
    for (int c = 0; c < NCH; ++c) {
        const float* y = sigb + (size_t)c * SIGSZ;

        float4 y1lo = *(const float4*)y;
        float4 y1hi = *(const float4*)(y + 4);
        float y1r[8] = {y1lo.x, y1lo.y, y1lo.z, y1lo.w, y1hi.x, y1hi.y, y1hi.z, y1hi.w};
        float y1a  = y[a];
        float y1b  = y[b8];
        float y2ab = y[8 + 8 * a + b8];
        float4 y2bc4 = *(const float4*)(y + 8 + 8 * b8 + CB);            // y2[b8, CB..CB+3]
        float4 y3own4 = *(const float4*)(y + 72 + 64 * a + 8 * b8 + CB); // y3[a,b8,CB..]

        float y2bcA[4]  = {y2bc4.x, y2bc4.y, y2bc4.z, y2bc4.w};
        float y3ownA[4] = {y3own4.x, y3own4.y, y3own4.z, y3own4.w};

#pragma unroll
        for (int j = 0; j < 4; ++j) {
            const int cc = CB + j;
            float y1c = y1r[cc];
            const float* y2r = y + 8 + 8 * cc;              // y2[cc,:]
            float4 y2lo = *(const float4*)y2r;
            float4 y2hi = *(const float4*)(y2r + 4);
            const float* y3r = y + 72 + 8 * (8 * b8 + cc);  // y3[b8,cc,:]
            float4 y3lo = *(const float4*)y3r;
            float4 y3hi = *(const float4*)(y3r + 4);
            const float* y4r = y + 584 + 8 * (64 * a + 8 * b8 + cc);
            float4 y4lo = *(const float4*)y4r;
            float4 y4hi = *(const float4*)(y4r + 4);
            float y2v[8] = {y2lo.x, y2lo.y, y2lo.z, y2lo.w, y2hi.x, y2hi.y, y2hi.z, y2hi.w};
            float y3v[8] = {y3lo.x, y3lo.y, y3lo.z, y3lo.w, y3hi.x, y3hi.y, y3hi.z, y3hi.w};
            float y4v[8] = {y4lo.x, y4lo.y, y4lo.z, y4lo.w, y4hi.x, y4hi.y, y4hi.z, y4hi.w};

#pragma unroll
            for (int d = 0; d < 8; ++d)
                x4[j][d] = x4[j][d] + x3[j] * y1r[d] + x2ab * y2v[d] + x1a * y3v[d] + y4v[d];

            x3[j]    = x3[j] + x2ab * y1c + x1a * y2bcA[j] + y3ownA[j];
            x2own[j] = x2own[j] + x1b * y1c + y2bcA[j];
            x1c[j]  += y1c;
        }
        x2ab = x2ab + x1a * y1b + y2ab;
        x1a += y1a; x1b += y1b;
    }

    // ---- outputs: tg = 64a + 8*b8 + CB + j ----
    if (a == 0 && b8 == 0) {
#pragma unroll
        for (int j = 0; j < 4; ++j) o[CB + j] = x1c[j];     // level-1
    }
    if (a == 0) {
#pragma unroll
        for (int j = 0; j < 4; ++j) o[8 + 8 * b8 + CB + j] = x2own[j];  // level-2
    }
    *(float4*)(o + 72 + 64 * a + 8 * b8 + CB) = make_float4(x3[0], x3[1], x3[2], x3[3]);
#pragma unroll
    for (int j = 0; j < 4; ++j) {
        float* p4 = o + 584 + 8 * (64 * a + 8 * b8 + CB + j);
        *(float4*)(p4)     = make_float4(x4[j][0], x4[j][1], x4[j][2], x4[j][3]);
        *(float4*)(p4 + 4) = make_float4(x4[j][4], x4[j][5], x4[j][6], x4[j][7]);
    }
}

// ---------------- fused kernel ----------------
__global__ __launch_bounds__(128)
void sig_fused(const float* __restrict__ path, float* __restrict__ ws,
               float* __restrict__ out) {
    const int blk = blockIdx.x;
    const int b   = blk >> 3;                     // batch
    const int c   = blk & 7;                      // chunk
    const int tid = threadIdx.x;
    const int t0  = c * CH;

    __shared__ float dxs[(CH + 1) * 8];           // +1 zero pad row
    __shared__ int lastFlag;
    {
        const float* p = path + (((size_t)b * Sc + t0) << 3);
#pragma unroll
        for (int i = tid; i < (CH + 1) * 8; i += 128) {
            float v = 0.f;
            if (t0 * 8 + i < Tc * 8 && i < CH * 8) v = p[i + 8] - p[i];
            dxs[i] = v;
        }
    }
    __syncthreads();

    const int half = tid >> 6;
    const int a    = (tid >> 3) & 7;
    const int b8   = tid & 7;
    const int k    = tid & 63;

    float acc4[4][8];
#pragma unroll
    for (int j = 0; j < 4; ++j)
#pragma unroll
        for (int d = 0; d < 8; ++d) acc4[j][d] = 0.f;
    float acc3[4] = {0.f, 0.f, 0.f, 0.f};
    float s2ab = 0.f, s1a = 0.f;

    if (half == 0) run_loop<0>(dxs, a, b8, acc4, acc3, s2ab, s1a);
    else           run_loop<4>(dxs, a, b8, acc4, acc3, s2ab, s1a);

    // ---- write chunk signature ----
    float* o = ws + CNTF + (size_t)blk * SIGSZ;
    if (half == 0) {
        if (b8 == 0) o[a] = s1a;
        o[8 + k] = s2ab;
    }
    *(float4*)(o + 72 + k * 8 + half * 4) = make_float4(acc3[0], acc3[1], acc3[2], acc3[3]);
#pragma unroll
    for (int j = 0; j < 4; ++j) {
        float* p4 = o + 584 + k * 64 + (half * 4 + j) * 8;
        *(float4*)(p4)     = make_float4(acc4[j][0], acc4[j][1], acc4[j][2], acc4[j][3]);
        *(float4*)(p4 + 4) = make_float4(acc4[j][4], acc4[j][5], acc4[j][6], acc4[j][7]);
    }

    // ---- last block of this batch folds ----
    __threadfence();                              // release sig writes
    if (tid == 0) {
        int* cnt = (int*)ws;
        int old = atomicAdd(&cnt[b], 1);          // device-scope
        lastFlag = (old == NCH - 1);
    }
    __syncthreads();
    if (!lastFlag) return;
    __threadfence();                              // acquire others' sig writes

    const float* sigb = ws + CNTF + (size_t)(b * NCH) * SIGSZ;
    float* ob = out + (size_t)b * SIGSZ;
    if (half == 0) combine_batch<0>(sigb, ob, a, b8);
    else           combine_batch<4>(sigb, ob, a, b8);
}

// ---------------- Fallback (single-kernel, used if ws too small) ----------------
__global__ __launch_bounds__(512)
void sig_fallback(const float* __restrict__ path, float* __restrict__ out) {
    const int b = blockIdx.x, tid = threadIdx.x;
    __shared__ float dxAll[Tc * 8];
    const float* prow = path + (size_t)b * Sc * 8;
    for (int n = tid; n < Tc * 8; n += 512) dxAll[n] = prow[n + 8] - prow[n];
    __syncthreads();

    const int aa = tid >> 6, bb = (tid >> 3) & 7, cc = tid & 7;
    float acc4[8] = {0.f, 0.f, 0.f, 0.f, 0.f, 0.f, 0.f, 0.f};
    float acc3 = 0.f, s2ab = 0.f, acc2 = 0.f, s1a = 0.f, s1b = 0.f, s1c = 0.f;
    for (int t = 0; t < Tc; ++t) {
        const float* r = &dxAll[t * 8];
        float4 lo = *(const float4*)r;
        float4 hi = *(const float4*)(r + 4);
        float da = r[aa], db = r[bb], dc = r[cc];
        float e = db * dc;
        float K = acc3 + s2ab * (0.5f * dc) + e * fmaf(s1a, 1.f / 6.f, da * (1.f / 24.f));
        acc4[0] = fmaf(lo.x, K, acc4[0]);
        acc4[1] = fmaf(lo.y, K, acc4[1]);
        acc4[2] = fmaf(lo.z, K, acc4[2]);
        acc4[3] = fmaf(lo.w, K, acc4[3]);
        acc4[4] = fmaf(hi.x, K, acc4[4]);
        acc4[5] = fmaf(hi.y, K, acc4[5]);
        acc4[6] = fmaf(hi.z, K, acc4[6]);
        acc4[7] = fmaf(hi.w, K, acc4[7]);
        acc3 = acc3 + s2ab * dc + e * fmaf(0.5f, s1a, da * (1.f / 6.f));
        acc2 = fmaf(s1b, dc, fmaf(0.5f, e, acc2));
        s2ab = fmaf(s1a, db, fmaf(0.5f * da, db, s2ab));
        s1a += da; s1b += db; s1c += dc;
    }
    float* o = out + (size_t)b * SIGSZ;
    if (tid < 8)  o[tid] = s1c;
    if (tid < 64) o[8 + tid] = acc2;
    o[72 + tid] = acc3;
    *(float4*)(o + 584 + 8 * tid)     = make_float4(acc4[0], acc4[1], acc4[2], acc4[3]);
    *(float4*)(o + 584 + 8 * tid + 4) = make_float4(acc4[4], acc4[5], acc4[6], acc4[7]);
}

extern "C" void kernel_launch(void* const* d_in, const int* in_sizes, int n_in,
                              void* d_out, int out_size, void* d_ws, size_t ws_size,
                              hipStream_t stream) {
    const float* path = (const float*)d_in[0];
    float* out = (float*)d_out;
    const size_t need = (size_t)(CNTF + Bc * NCH * SIGSZ) * sizeof(float);  // ~19.2 MB
    if (ws_size >= need) {
        float* ws = (float*)d_ws;
        hipMemsetAsync(ws, 0, CNTF * sizeof(int), stream);   // zero batch counters
        sig_fused<<<dim3(Bc * NCH), dim3(128), 0, stream>>>(path, ws, out);
    } else {
        sig_fallback<<<dim3(Bc), dim3(512), 0, stream>>>(path, out);
    }
}

// Round 10
// 30.429 us; speedup vs baseline: 6.4542x; 6.4542x over previous
//
#include <hip/hip_runtime.h>

// Truncated path signature, trunc=4, D=8, B=128, S=512.
// Phase 1 (sig_chunk): 1024 blocks (128 batches x 8 chunks of 64 steps),
//   128 threads (2 waves). Lane = (a,b); wave id selects c-range {4h..4h+3}
//   via template<CB>. Lane state: acc4[4][8], acc3[4], s2ab, s1a.
//   Step algebra factored through g = 0.5*s2ab + db*v, h = s2ab + db*w:
//   K_j = fma(dc_j, g, acc3_j), acc3_j = fma(dc_j, h, acc3_j)  (51 VALU/step).
// Phase 2 (sig_combine): 128 blocks x 512 thr; per chunk, levels 1-3 of y
//   (584 floats) are STAGED IN LDS once per block; only the per-thread y4 row
//   comes from global. Fold order 0..7 (deterministic).

constexpr int Bc = 128, Sc = 512, Tc = 511;
constexpr int NCH = 8, CH = 64;
constexpr int SIGSZ = 8 + 64 + 512 + 4096;        // 4680 floats

// ---------------- Phase 1 inner loop (CB = 4*waveid, compile-time) ----------------
template <int CB>
__device__ __forceinline__ void run_loop(
    const float* __restrict__ dxs, int a, int bcoord,
    float acc4[4][8], float acc3[4], float& s2ab, float& s1a)
{
#pragma unroll 4
    for (int t = 0; t < CH; ++t) {
        const float* rp = &dxs[t * 8];
        float4 lo = *(const float4*)rp;           // broadcast b128
        float4 hi = *(const float4*)(rp + 4);     // broadcast b128
        float r[8] = {lo.x, lo.y, lo.z, lo.w, hi.x, hi.y, hi.z, hi.w};
        float da = rp[a];                         // LDS b32, conflict-free
        float db = rp[bcoord];                    // LDS b32, conflict-free

        float v = fmaf(s1a, 1.f / 6.f, da * (1.f / 24.f));
        float w = fmaf(0.5f, s1a, da * (1.f / 6.f));
        float g = fmaf(db, v, 0.5f * s2ab);       // K_j  = acc3_j + dc_j * g
        float h = fmaf(db, w, s2ab);              // acc3_j += dc_j * h

#pragma unroll
        for (int j = 0; j < 4; ++j) {
            float dc = r[CB + j];                 // compile-time index
            float K = fmaf(dc, g, acc3[j]);
#pragma unroll
            for (int d = 0; d < 8; ++d)
                acc4[j][d] = fmaf(r[d], K, acc4[j][d]);
            acc3[j] = fmaf(dc, h, acc3[j]);
        }
        s2ab = fmaf(s1a, db, fmaf(0.5f * da, db, s2ab));
        s1a += da;
    }
}

// ---------------- Phase 1: per-chunk signature ----------------
__global__ __launch_bounds__(128)
void sig_chunk(const float* __restrict__ path, float* __restrict__ ws) {
    const int blk = blockIdx.x;
    const int b   = blk >> 3;                     // batch
    const int c   = blk & 7;                      // chunk
    const int tid = threadIdx.x;
    const int t0  = c * CH;

    __shared__ float dxs[CH * 8];                 // 2 KiB
    {
        const float* p = path + (((size_t)b * Sc + t0) << 3);
#pragma unroll
        for (int i = tid; i < CH * 8; i += 128) {
            float v = 0.f;
            if (t0 * 8 + i < Tc * 8) v = p[i + 8] - p[i];   // tail row -> 0
            dxs[i] = v;
        }
    }
    __syncthreads();                              // only barrier

    const int half   = tid >> 6;                  // wave id (0/1)
    const int a      = (tid >> 3) & 7;
    const int bcoord = tid & 7;
    const int k      = tid & 63;                  // (a,b) pair index

    float acc4[4][8];
#pragma unroll
    for (int j = 0; j < 4; ++j)
#pragma unroll
        for (int d = 0; d < 8; ++d) acc4[j][d] = 0.f;
    float acc3[4] = {0.f, 0.f, 0.f, 0.f};
    float s2ab = 0.f, s1a = 0.f;

    if (half == 0) run_loop<0>(dxs, a, bcoord, acc4, acc3, s2ab, s1a);
    else           run_loop<4>(dxs, a, bcoord, acc4, acc3, s2ab, s1a);

    // ---- write signature: [s1(8) | s2(64) | s3(512) | s4(4096)] ----
    float* o = ws + (size_t)blk * SIGSZ;
    if (half == 0) {
        if (bcoord == 0) o[a] = s1a;              // level-1 elem a
        o[8 + k] = s2ab;                          // level-2 elem (a,b)
    }
    *(float4*)(o + 72 + k * 8 + half * 4) = make_float4(acc3[0], acc3[1], acc3[2], acc3[3]);
#pragma unroll
    for (int j = 0; j < 4; ++j) {
        float* p4 = o + 584 + k * 64 + (half * 4 + j) * 8;
        *(float4*)(p4)     = make_float4(acc4[j][0], acc4[j][1], acc4[j][2], acc4[j][3]);
        *(float4*)(p4 + 4) = make_float4(acc4[j][4], acc4[j][5], acc4[j][6], acc4[j][7]);
    }
}

// ---------------- Phase 2: fold chunk signatures (LDS-staged) ----------------
__global__ __launch_bounds__(512)
void sig_combine(const float* __restrict__ ws, float* __restrict__ out) {
    const int b = blockIdx.x, tid = threadIdx.x;
    const int aa = tid >> 6, bb = (tid >> 3) & 7, cc = tid & 7;

    __shared__ __align__(16) float ylds[584];     // levels 1-3 of current chunk

    float x4[8] = {0.f, 0.f, 0.f, 0.f, 0.f, 0.f, 0.f, 0.f};
    float x3 = 0.f, x2ab = 0.f, x2own = 0.f;
    float x1a = 0.f, x1b = 0.f, x1c = 0.f;

    for (int c = 0; c < NCH; ++c) {
        const float* y = ws + ((size_t)(b * NCH + c)) * SIGSZ;

        // stage y[0..584) into LDS (146 float4 loads, coalesced)
        if (tid < 146)
            *(float4*)(ylds + 4 * tid) = *(const float4*)(y + 4 * tid);
        __syncthreads();

        float y1a = ylds[aa], y1b = ylds[bb], y1c = ylds[cc];
        float y2ab = ylds[8 + 8 * aa + bb];
        float y2bc = ylds[8 + 8 * bb + cc];
        float4 y1lo = *(const float4*)ylds;
        float4 y1hi = *(const float4*)(ylds + 4);
        const float* y2r = ylds + 8 + 8 * cc;
        float4 y2lo = *(const float4*)y2r;
        float4 y2hi = *(const float4*)(y2r + 4);
        const float* y3r = ylds + 72 + 8 * (tid & 63);
        float4 y3lo = *(const float4*)y3r;
        float4 y3hi = *(const float4*)(y3r + 4);
        float y3own = ylds[72 + tid >= 584 ? 0 : 72 + tid];   // guarded below
        // NOTE: 72+tid < 584 for tid < 512 always (72+511=583) -> direct:
        y3own = ylds[72 + tid];
        const float* y4r = y + 584 + 8 * tid;                 // global, per-thread
        float4 y4lo = *(const float4*)y4r;
        float4 y4hi = *(const float4*)(y4r + 4);

        x4[0] = x4[0] + x3 * y1lo.x + x2ab * y2lo.x + x1a * y3lo.x + y4lo.x;
        x4[1] = x4[1] + x3 * y1lo.y + x2ab * y2lo.y + x1a * y3lo.y + y4lo.y;
        x4[2] = x4[2] + x3 * y1lo.z + x2ab * y2lo.z + x1a * y3lo.z + y4lo.z;
        x4[3] = x4[3] + x3 * y1lo.w + x2ab * y2lo.w + x1a * y3lo.w + y4lo.w;
        x4[4] = x4[4] + x3 * y1hi.x + x2ab * y2hi.x + x1a * y3hi.x + y4hi.x;
        x4[5] = x4[5] + x3 * y1hi.y + x2ab * y2hi.y + x1a * y3hi.y + y4hi.y;
        x4[6] = x4[6] + x3 * y1hi.z + x2ab * y2hi.z + x1a * y3hi.z + y4hi.z;
        x4[7] = x4[7] + x3 * y1hi.w + x2ab * y2hi.w + x1a * y3hi.w + y4hi.w;

        x3 = x3 + x2ab * y1c + x1a * y2bc + y3own;
        x2ab  = x2ab  + x1a * y1b + y2ab;
        x2own = x2own + x1b * y1c + y2bc;
        x1a += y1a; x1b += y1b; x1c += y1c;

        __syncthreads();                          // before next chunk's staging
    }

    float* o = out + (size_t)b * SIGSZ;
    if (tid < 8)  o[tid] = x1c;
    if (tid < 64) o[8 + tid] = x2own;
    o[72 + tid] = x3;
    *(float4*)(o + 584 + 8 * tid)     = make_float4(x4[0], x4[1], x4[2], x4[3]);
    *(float4*)(o + 584 + 8 * tid + 4) = make_float4(x4[4], x4[5], x4[6], x4[7]);
}

// ---------------- Fallback (single-kernel, used if ws too small) ----------------
__global__ __launch_bounds__(512)
void sig_fallback(const float* __restrict__ path, float* __restrict__ out) {
    const int b = blockIdx.x, tid = threadIdx.x;
    __shared__ float dxAll[Tc * 8];
    const float* prow = path + (size_t)b * Sc * 8;
    for (int n = tid; n < Tc * 8; n += 512) dxAll[n] = prow[n + 8] - prow[n];
    __syncthreads();

    const int aa = tid >> 6, bb = (tid >> 3) & 7, cc = tid & 7;
    float acc4[8] = {0.f, 0.f, 0.f, 0.f, 0.f, 0.f, 0.f, 0.f};
    float acc3 = 0.f, s2ab = 0.f, acc2 = 0.f, s1a = 0.f, s1b = 0.f, s1c = 0.f;
    for (int t = 0; t < Tc; ++t) {
        const float* r = &dxAll[t * 8];
        float4 lo = *(const float4*)r;
        float4 hi = *(const float4*)(r + 4);
        float da = r[aa], db = r[bb], dc = r[cc];
        float e = db * dc;
        float K = acc3 + s2ab * (0.5f * dc) + e * fmaf(s1a, 1.f / 6.f, da * (1.f / 24.f));
        acc4[0] = fmaf(lo.x, K, acc4[0]);
        acc4[1] = fmaf(lo.y, K, acc4[1]);
        acc4[2] = fmaf(lo.z, K, acc4[2]);
        acc4[3] = fmaf(lo.w, K, acc4[3]);
        acc4[4] = fmaf(hi.x, K, acc4[4]);
        acc4[5] = fmaf(hi.y, K, acc4[5]);
        acc4[6] = fmaf(hi.z, K, acc4[6]);
        acc4[7] = fmaf(hi.w, K, acc4[7]);
        acc3 = acc3 + s2ab * dc + e * fmaf(0.5f, s1a, da * (1.f / 6.f));
        acc2 = fmaf(s1b, dc, fmaf(0.5f, e, acc2));
        s2ab = fmaf(s1a, db, fmaf(0.5f * da, db, s2ab));
        s1a += da; s1b += db; s1c += dc;
    }
    float* o = out + (size_t)b * SIGSZ;
    if (tid < 8)  o[tid] = s1c;
    if (tid < 64) o[8 + tid] = acc2;
    o[72 + tid] = acc3;
    *(float4*)(o + 584 + 8 * tid)     = make_float4(acc4[0], acc4[1], acc4[2], acc4[3]);
    *(float4*)(o + 584 + 8 * tid + 4) = make_float4(acc4[4], acc4[5], acc4[6], acc4[7]);
}

extern "C" void kernel_launch(void* const* d_in, const int* in_sizes, int n_in,
                              void* d_out, int out_size, void* d_ws, size_t ws_size,
                              hipStream_t stream) {
    const float* path = (const float*)d_in[0];
    float* out = (float*)d_out;
    const size_t need = (size_t)Bc * NCH * SIGSZ * sizeof(float);   // ~19.2 MB
    if (ws_size >= need) {
        float* ws = (float*)d_ws;
        sig_chunk  <<<dim3(Bc * NCH), dim3(128), 0, stream>>>(path, ws);
        sig_combine<<<dim3(Bc), dim3(512), 0, stream>>>(ws, out);
    } else {
        sig_fallback<<<dim3(Bc), dim3(512), 0, stream>>>(path, out);
    }
}